// Round 2
// baseline (233.393 us; speedup 1.0000x reference)
//
#include <hip/hip_runtime.h>
#include <hip/hip_bf16.h>
#include <math.h>

// Problem constants
#define NB   8
#define TCTX 4096
#define ED   1024
#define KD   64

typedef __attribute__((ext_vector_type(8))) short bf16x8;
typedef __attribute__((ext_vector_type(4))) float f32x4;

__device__ __forceinline__ unsigned short f2bf(float f) {
    union { float f; unsigned u; } c; c.f = f;
    return (unsigned short)((c.u + 0x7FFFu + ((c.u >> 16) & 1u)) >> 16);
}
__device__ __forceinline__ unsigned pk2(float a, float b) {
    return (unsigned)f2bf(a) | ((unsigned)f2bf(b) << 16);
}
// LDS tiles with 128-byte rows; XOR-swizzle 16B blocks to kill bank conflicts.
__device__ __forceinline__ int swz(int row, int byteoff) {
    return row * 128 + (byteoff ^ ((row & 7) << 4));
}
// 256-byte-row variant (proj V-transpose bounce buffer)
__device__ __forceinline__ int swzV(int row, int byteoff) {
    return row * 256 + (byteoff ^ ((row & 7) << 4));
}
__device__ __forceinline__ f32x4 fzero4() {
    f32x4 z; z[0] = 0.f; z[1] = 0.f; z[2] = 0.f; z[3] = 0.f; return z;
}

// ---------------------------------------------------------------------------
// Projection kernel: for 128 rows per block compute
//   keys    = relu(relu(emb@kw1^T + kb1)@kw2^T + kb2)   -> Ko [b*T+t][h]
//   queries = relu(relu(emb@qw1^T + qb1)@qw2^T + qb2)   -> Qo [b*T+t][h]
//   values  = emb@vw^T + vb                             -> Vt [b][h][t]  (TRANSPOSED)
// First layer: one MFMA GEMM with B = concat(kw1,qw1,vw) (192 cols).
// Second layers fused via per-wave LDS round-trip. V transposed via LDS bounce
// so the attention PV MFMA can consume V in [h][s] orientation (B-operand
// convention: lane c must hold V[s=k][h=c], i.e. rows of Vt).
// ---------------------------------------------------------------------------
__global__ __launch_bounds__(256) void proj_kernel(
    const float* __restrict__ emb,
    const float* __restrict__ kw1, const float* __restrict__ kb1,
    const float* __restrict__ kw2, const float* __restrict__ kb2,
    const float* __restrict__ qw1, const float* __restrict__ qb1,
    const float* __restrict__ qw2, const float* __restrict__ qb2,
    const float* __restrict__ vw,  const float* __restrict__ vb,
    unsigned short* __restrict__ Qo, unsigned short* __restrict__ Ko,
    unsigned short* __restrict__ Vt)
{
    __shared__ __align__(16) char lds[56 * 1024];
    char* As = lds;               // [128 rows][128B]  emb tile (bf16); later VT bounce
    char* Bs = lds + 16 * 1024;   // [192 rows][128B]  W1cat tile (bf16)
    char* W2 = lds + 40 * 1024;   // [128 rows][128B]  kw2 rows 0-63, qw2 rows 64-127

    const int tid  = threadIdx.x;
    const int lane = tid & 63;
    const int w    = tid >> 6;     // wave 0..3, owns rows w*32..w*32+31
    const int lr   = lane & 15;
    const int lg   = lane >> 4;
    const long r0  = (long)blockIdx.x * 128;
    const int  b   = blockIdx.x >> 5;            // 32 blocks per batch
    const int  tb  = (blockIdx.x & 31) * 128;    // t base within batch

    // stage second-layer weights once (2048 float4)
    #pragma unroll
    for (int it = 0; it < 8; ++it) {
        int f4 = it * 256 + tid;
        int row = f4 >> 4, c4 = f4 & 15;
        const float* src = (row < 64) ? (kw2 + row * 64 + c4 * 4)
                                      : (qw2 + (row - 64) * 64 + c4 * 4);
        float4 v = *(const float4*)src;
        *(uint2*)(W2 + swz(row, c4 * 8)) = make_uint2(pk2(v.x, v.y), pk2(v.z, v.w));
    }

    f32x4 acc[2][12];
    #pragma unroll
    for (int i = 0; i < 2; ++i)
        #pragma unroll
        for (int j = 0; j < 12; ++j) acc[i][j] = fzero4();

    for (int ks = 0; ks < 16; ++ks) {
        const int k0 = ks * 64;
        __syncthreads();   // previous iter's reads done before overwrite
        // stage A: emb[128][64] fp32 -> bf16 (2048 float4)
        #pragma unroll
        for (int it = 0; it < 8; ++it) {
            int f4 = it * 256 + tid;
            int row = f4 >> 4, c4 = f4 & 15;
            float4 v = *(const float4*)(emb + (r0 + row) * ED + k0 + c4 * 4);
            *(uint2*)(As + swz(row, c4 * 8)) = make_uint2(pk2(v.x, v.y), pk2(v.z, v.w));
        }
        // stage B: W1cat[192][64] fp32 -> bf16 (3072 float4)
        #pragma unroll
        for (int it = 0; it < 12; ++it) {
            int f4 = it * 256 + tid;
            int row = f4 >> 4, c4 = f4 & 15;
            const float* src = (row < 64)  ? (kw1 + row * ED)
                             : (row < 128) ? (qw1 + (row - 64) * ED)
                                           : (vw  + (row - 128) * ED);
            float4 v = *(const float4*)(src + k0 + c4 * 4);
            *(uint2*)(Bs + swz(row, c4 * 8)) = make_uint2(pk2(v.x, v.y), pk2(v.z, v.w));
        }
        __syncthreads();
        #pragma unroll
        for (int kh = 0; kh < 2; ++kh) {
            bf16x8 a[2], bb[12];
            #pragma unroll
            for (int mi = 0; mi < 2; ++mi)
                a[mi] = *(bf16x8*)(As + swz(w * 32 + mi * 16 + lr, kh * 64 + lg * 16));
            #pragma unroll
            for (int n = 0; n < 12; ++n)
                bb[n] = *(bf16x8*)(Bs + swz(n * 16 + lr, kh * 64 + lg * 16));
            #pragma unroll
            for (int mi = 0; mi < 2; ++mi)
                #pragma unroll
                for (int n = 0; n < 12; ++n)
                    acc[mi][n] = __builtin_amdgcn_mfma_f32_16x16x32_bf16(
                        a[mi], bb[n], acc[mi][n], 0, 0, 0);
        }
    }
    __syncthreads();   // all waves done reading As/Bs; As space reused below

    // per-wave private h1 buffer [32][128B] overlaid on As
    char* H = As + w * 4096;

    #pragma unroll
    for (int kq = 0; kq < 2; ++kq) {
        const float* b1 = kq ? qb1 : kb1;
        const float* b2 = kq ? qb2 : kb2;
        unsigned short* dst = kq ? Qo : Ko;
        // h1 = relu(acc + b1) -> bf16 -> H  (C-layout: col=lr, row=lg*4+rr)
        #pragma unroll
        for (int mi = 0; mi < 2; ++mi)
            #pragma unroll
            for (int n = 0; n < 4; ++n) {
                int col = n * 16 + lr;
                float bias = b1[col];
                #pragma unroll
                for (int rr = 0; rr < 4; ++rr) {
                    int row = mi * 16 + lg * 4 + rr;
                    float hv = fmaxf(acc[mi][kq * 4 + n][rr] + bias, 0.f);
                    *(unsigned short*)(H + swz(row, col * 2)) = f2bf(hv);
                }
            }
        // second layer: [32x64] @ [64x64]^T
        f32x4 acc2[2][4];
        #pragma unroll
        for (int mi = 0; mi < 2; ++mi)
            #pragma unroll
            for (int n = 0; n < 4; ++n) acc2[mi][n] = fzero4();
        #pragma unroll
        for (int kh = 0; kh < 2; ++kh) {
            bf16x8 a2[2], w2f[4];
            #pragma unroll
            for (int mi = 0; mi < 2; ++mi)
                a2[mi] = *(bf16x8*)(H + swz(mi * 16 + lr, kh * 64 + lg * 16));
            #pragma unroll
            for (int n = 0; n < 4; ++n)
                w2f[n] = *(bf16x8*)(W2 + swz(kq * 64 + n * 16 + lr, kh * 64 + lg * 16));
            #pragma unroll
            for (int mi = 0; mi < 2; ++mi)
                #pragma unroll
                for (int n = 0; n < 4; ++n)
                    acc2[mi][n] = __builtin_amdgcn_mfma_f32_16x16x32_bf16(
                        a2[mi], w2f[n], acc2[mi][n], 0, 0, 0);
        }
        // relu(acc2 + b2) -> bf16 -> global
        #pragma unroll
        for (int mi = 0; mi < 2; ++mi)
            #pragma unroll
            for (int n = 0; n < 4; ++n) {
                int col = n * 16 + lr;
                float bias = b2[col];
                #pragma unroll
                for (int rr = 0; rr < 4; ++rr) {
                    long rg = r0 + w * 32 + mi * 16 + lg * 4 + rr;
                    dst[rg * KD + col] = f2bf(fmaxf(acc2[mi][n][rr] + bias, 0.f));
                }
            }
    }

    // ---- values, transposed: Vt[b][h][t] via LDS bounce -------------------
    __syncthreads();            // all waves done with H (overlaid on As)
    char* VT = As;              // [64 h][256B (=128 t_local bf16)]
    #pragma unroll
    for (int mi = 0; mi < 2; ++mi)
        #pragma unroll
        for (int n = 0; n < 4; ++n) {
            int col = n * 16 + lr;        // h
            float bias = vb[col];
            #pragma unroll
            for (int rr = 0; rr < 4; ++rr) {
                int tl = w * 32 + mi * 16 + lg * 4 + rr;   // t_local 0..127
                *(unsigned short*)(VT + swzV(col, tl * 2)) =
                    f2bf(acc[mi][8 + n][rr] + bias);
            }
        }
    __syncthreads();
    // coalesced copy out: 64 rows x 256B = 1024 int4, 256 threads x 4
    #pragma unroll
    for (int it = 0; it < 4; ++it) {
        int c = it * 256 + tid;
        int h = c >> 4, c4 = c & 15;      // 16 int4 per row
        *(int4*)(Vt + ((long)b * KD + h) * TCTX + tb + c4 * 8) =
            *(int4*)(VT + swzV(h, c4 * 16));
    }
}

// ---------------------------------------------------------------------------
// Flash attention with the reference's exact mask semantics:
// masked (s<=t) entries get score = -1e10f (matches fp32 `score + -1e10`).
// QB=64 q-rows/block (4 waves x 16 rows), online softmax in fp32.
// Last q-tile sweeps all s-tiles (row 4095 fully masked -> uniform softmax).
// V consumed from Vt[b][h][t] so the PV B-operand reads rows of [h][s].
// ---------------------------------------------------------------------------
__global__ __launch_bounds__(256) void attn_kernel(
    const unsigned short* __restrict__ Qb,
    const unsigned short* __restrict__ Kb,
    const unsigned short* __restrict__ Vt,
    float* __restrict__ out)
{
    __shared__ __align__(16) char lds[32 * 1024];
    char* Qs = lds;                // [64 q][128B]
    char* Ks = lds + 8 * 1024;     // [64 s][128B]
    char* Vs = lds + 16 * 1024;    // [64 h][128B]  (rows = h, cols = s)
    char* Ps = lds + 24 * 1024;    // 4 x [16][128B] per-wave P tiles

    const int bid = blockIdx.x;
    const int b   = bid & 7;
    const int qr  = bid >> 3;
    const int qi  = (qr + 63) & 63;   // rotate so the heavy full-sweep tile launches first
    const int t0  = qi * 64;
    const int tid = threadIdx.x, lane = tid & 63, w = tid >> 6;
    const int lr  = lane & 15, lg = lane >> 4;

    // stage Q tile once
    const unsigned short* Qg = Qb + ((long)b * TCTX + t0) * KD;
    #pragma unroll
    for (int it = 0; it < 2; ++it) {
        int c = it * 256 + tid;
        int row = c >> 3, cb = c & 7;
        *(int4*)(Qs + swz(row, cb * 16)) = *(const int4*)(Qg + row * KD + cb * 8);
    }

    float m_[4], sum_[4];
    f32x4 O[4];
    #pragma unroll
    for (int rr = 0; rr < 4; ++rr) { m_[rr] = -INFINITY; sum_[rr] = 0.f; }
    #pragma unroll
    for (int n = 0; n < 4; ++n) O[n] = fzero4();

    const int s_begin = (qi == 63) ? 0 : qi;
    for (int si = s_begin; si < 64; ++si) {
        const int s0 = si * 64;
        __syncthreads();
        const unsigned short* Kg = Kb + ((long)b * TCTX + s0) * KD;
        const unsigned short* Vg = Vt + (long)b * KD * TCTX + s0;
        #pragma unroll
        for (int it = 0; it < 2; ++it) {
            int c = it * 256 + tid;
            int row = c >> 3, cb = c & 7;
            *(int4*)(Ks + swz(row, cb * 16)) = *(const int4*)(Kg + row * KD + cb * 8);
            // V^T tile: row = h, cols = s0..s0+63 of Vt[b][h][:]
            *(int4*)(Vs + swz(row, cb * 16)) = *(const int4*)(Vg + (long)row * TCTX + cb * 8);
        }
        __syncthreads();

        // QK^T: wave w handles q-rows w*16..w*16+15, all 64 s
        f32x4 sc[4];
        #pragma unroll
        for (int n = 0; n < 4; ++n) sc[n] = fzero4();
        #pragma unroll
        for (int kh = 0; kh < 2; ++kh) {
            bf16x8 a = *(bf16x8*)(Qs + swz(w * 16 + lr, kh * 64 + lg * 16));
            #pragma unroll
            for (int n = 0; n < 4; ++n) {
                bf16x8 bk = *(bf16x8*)(Ks + swz(n * 16 + lr, kh * 64 + lg * 16));
                sc[n] = __builtin_amdgcn_mfma_f32_16x16x32_bf16(a, bk, sc[n], 0, 0, 0);
            }
        }

        // masked scores (faithful fp32 semantics)
        float p[4][4];   // [n][rr]
        #pragma unroll
        for (int n = 0; n < 4; ++n) {
            int sg = s0 + n * 16 + lr;
            #pragma unroll
            for (int rr = 0; rr < 4; ++rr) {
                int tg = t0 + w * 16 + lg * 4 + rr;
                float v = sc[n][rr] * 0.125f;
                if (sg <= tg) v = -1e10f;
                p[n][rr] = v;
            }
        }
        // online softmax per q-row (16-lane groups share a row set)
        #pragma unroll
        for (int rr = 0; rr < 4; ++rr) {
            float mx = fmaxf(fmaxf(p[0][rr], p[1][rr]), fmaxf(p[2][rr], p[3][rr]));
            #pragma unroll
            for (int d = 1; d < 16; d <<= 1) mx = fmaxf(mx, __shfl_xor(mx, d, 64));
            float mn = fmaxf(m_[rr], mx);
            float scl = __expf(m_[rr] - mn);
            m_[rr] = mn;
            float ls = 0.f;
            #pragma unroll
            for (int n = 0; n < 4; ++n) { p[n][rr] = __expf(p[n][rr] - mn); ls += p[n][rr]; }
            #pragma unroll
            for (int d = 1; d < 16; d <<= 1) ls += __shfl_xor(ls, d, 64);
            sum_[rr] = sum_[rr] * scl + ls;
            #pragma unroll
            for (int n = 0; n < 4; ++n) O[n][rr] *= scl;
        }

        // P -> LDS (bf16), per-wave private region
        char* Pw = Ps + w * 2048;
        #pragma unroll
        for (int n = 0; n < 4; ++n) {
            int col = n * 16 + lr;
            #pragma unroll
            for (int rr = 0; rr < 4; ++rr) {
                int row = lg * 4 + rr;
                *(unsigned short*)(Pw + swz(row, col * 2)) = f2bf(p[n][rr]);
            }
        }
        // PV: O += P @ V   (B-operand = rows of Vs = [h][s] -> lane c holds V[s][h=c])
        #pragma unroll
        for (int kh = 0; kh < 2; ++kh) {
            bf16x8 ap = *(bf16x8*)(Pw + swz(lr, kh * 64 + lg * 16));
            #pragma unroll
            for (int n = 0; n < 4; ++n) {
                bf16x8 bv = *(bf16x8*)(Vs + swz(n * 16 + lr, kh * 64 + lg * 16));
                O[n] = __builtin_amdgcn_mfma_f32_16x16x32_bf16(ap, bv, O[n], 0, 0, 0);
            }
        }
    }

    // epilogue: out = O / sum
    #pragma unroll
    for (int n = 0; n < 4; ++n) {
        int col = n * 16 + lr;
        #pragma unroll
        for (int rr = 0; rr < 4; ++rr) {
            int tg = t0 + w * 16 + lg * 4 + rr;
            out[((long)b * TCTX + tg) * KD + col] = O[n][rr] / sum_[rr];
        }
    }
}

extern "C" void kernel_launch(void* const* d_in, const int* in_sizes, int n_in,
                              void* d_out, int out_size, void* d_ws, size_t ws_size,
                              hipStream_t stream) {
    const float* emb = (const float*)d_in[0];
    const float* kw1 = (const float*)d_in[1];
    const float* kb1 = (const float*)d_in[2];
    const float* kw2 = (const float*)d_in[3];
    const float* kb2 = (const float*)d_in[4];
    const float* qw1 = (const float*)d_in[5];
    const float* qb1 = (const float*)d_in[6];
    const float* qw2 = (const float*)d_in[7];
    const float* qb2 = (const float*)d_in[8];
    const float* vw  = (const float*)d_in[9];
    const float* vb  = (const float*)d_in[10];

    unsigned short* Qb = (unsigned short*)d_ws;                // 4 MB
    unsigned short* Kb = Qb + (size_t)NB * TCTX * KD;          // 4 MB
    unsigned short* Vt = Kb + (size_t)NB * TCTX * KD;          // 4 MB, [b][h][t]

    hipLaunchKernelGGL(proj_kernel, dim3(256), dim3(256), 0, stream,
                       emb, kw1, kb1, kw2, kb2, qw1, qb1, qw2, qb2, vw, vb,
                       Qb, Kb, Vt);
    hipLaunchKernelGGL(attn_kernel, dim3(512), dim3(256), 0, stream,
                       Qb, Kb, Vt, (float*)d_out);
}

// Round 4
// 148.499 us; speedup vs baseline: 1.5717x; 1.5717x over previous
//
#include <hip/hip_runtime.h>
#include <hip/hip_bf16.h>
#include <math.h>

// Problem constants
#define NB   8
#define TCTX 4096
#define ED   1024
#define KD   64

typedef __attribute__((ext_vector_type(8))) short bf16x8;
typedef __attribute__((ext_vector_type(4))) float f32x4;

__device__ __forceinline__ unsigned short f2bf(float f) {
    union { float f; unsigned u; } c; c.f = f;
    return (unsigned short)((c.u + 0x7FFFu + ((c.u >> 16) & 1u)) >> 16);
}
// LDS tiles with 128-byte rows; XOR-swizzle 16B blocks to kill bank conflicts.
__device__ __forceinline__ int swz(int row, int byteoff) {
    return row * 128 + (byteoff ^ ((row & 7) << 4));
}
__device__ __forceinline__ f32x4 fzero4() {
    f32x4 z; z[0] = 0.f; z[1] = 0.f; z[2] = 0.f; z[3] = 0.f; return z;
}
// async global->LDS, 16B per lane; LDS dest = wave-uniform base + lane*16
__device__ __forceinline__ void gl_lds16(const void* g, void* l) {
    __builtin_amdgcn_global_load_lds(
        (const __attribute__((address_space(1))) unsigned int*)g,
        (__attribute__((address_space(3))) unsigned int*)l, 16, 0, 0);
}

// ---------------------------------------------------------------------------
// Prep kernel: one-time weight repack (fp32 -> bf16).
//  W1p: 16 chunks (one per k-step) of the EXACT swizzled LDS image of
//       W1cat = concat(kw1,qw1,vw) [192 rows][64 k] bf16, rows=128B,
//       16B-block bb of row r holds k-block (bb ^ (r&7)). 384 KB.
//  W2p: kw2/qw2 in MFMA B-fragment order: [(kq*4+n)*2+kh][lane][8] so each
//       lane's 16B load is its fragment. 16 KB.
// ---------------------------------------------------------------------------
__global__ __launch_bounds__(256) void prep_kernel(
    const float* __restrict__ kw1, const float* __restrict__ qw1,
    const float* __restrict__ vw,  const float* __restrict__ kw2,
    const float* __restrict__ qw2,
    unsigned short* __restrict__ W1p, unsigned short* __restrict__ W2p)
{
    int idx = blockIdx.x * 256 + threadIdx.x;   // 16B-block index
    if (idx < 24576) {
        int ks = idx / 1536, rem = idx % 1536;
        int r = rem >> 3, bb = rem & 7;
        int c = bb ^ (r & 7);
        const float* src = (r < 64)  ? (kw1 + r * ED)
                         : (r < 128) ? (qw1 + (r - 64) * ED)
                                     : (vw  + (r - 128) * ED);
        src += ks * 64 + c * 8;
        unsigned short* dst = W1p + (size_t)idx * 8;
        #pragma unroll
        for (int e = 0; e < 8; ++e) dst[e] = f2bf(src[e]);
    } else if (idx < 25600) {
        int j = idx - 24576;
        int lane = j & 63, kh = (j >> 6) & 1, n = (j >> 7) & 3, kq = j >> 9;
        int row = n * 16 + (lane & 15);
        int ko  = kh * 32 + (lane >> 4) * 8;
        const float* src = (kq ? qw2 : kw2) + row * 64 + ko;
        unsigned short* dst = W2p + (size_t)j * 8;
        #pragma unroll
        for (int e = 0; e < 8; ++e) dst[e] = f2bf(src[e]);
    }
}

// ---------------------------------------------------------------------------
// Projection kernel, async-staged + double-buffered.
// 64 rows/block, 512 blocks, 4 waves; wave w owns rows w*16..w*16+15.
// A tile: emb fp32 [64][64k] = 16KB via global_load_lds with pre-swizzled
//   per-lane SOURCE (LDS dest linear); bf16 convert at fragment read.
// B tile: prepacked bf16 image, pure linear global_load_lds, 24KB.
// One __syncthreads per k-step; prefetch issued before compute.
// Outputs: Ko/Qo [b*T+t][h] bf16, Vt [b][h][t] bf16 (transposed via LDS).
// ---------------------------------------------------------------------------
__global__ __launch_bounds__(256, 2) void proj_kernel(
    const float* __restrict__ emb,
    const unsigned short* __restrict__ W1p, const unsigned short* __restrict__ W2p,
    const float* __restrict__ kb1, const float* __restrict__ kb2,
    const float* __restrict__ qb1, const float* __restrict__ qb2,
    const float* __restrict__ vb,
    unsigned short* __restrict__ Qo, unsigned short* __restrict__ Ko,
    unsigned short* __restrict__ Vt)
{
    __shared__ __align__(16) char lds[80 * 1024];
    // A buffers at 0 / 16KB (fp32 [64][256B]); B buffers at 32KB / 56KB (bf16 [192][128B])

    const int tid  = threadIdx.x;
    const int lane = tid & 63;
    const int w    = tid >> 6;
    const int lr   = lane & 15;
    const int lg   = lane >> 4;
    const long r0  = (long)blockIdx.x * 64;
    const int  b   = blockIdx.x >> 6;            // 64 blocks per batch
    const int  tb  = (blockIdx.x & 63) * 64;     // t base within batch

    const float* embB = emb + r0 * ED;

    f32x4 acc[12];
    #pragma unroll
    for (int j = 0; j < 12; ++j) acc[j] = fzero4();

    // ---- staging (async DMA) ----
    auto stageA = [&](int buf, int ks) {
        char* Abuf = lds + buf * 16 * 1024;
        const float* eb = embB + ks * 64;
        #pragma unroll
        for (int j = 0; j < 4; ++j) {
            int chunk = j * 4 + w;                    // 1KB chunks
            int r = chunk * 4 + (lane >> 4);          // 4 rows per chunk
            int c = (lane & 15) ^ (r & 7);            // pre-swizzled source
            gl_lds16(eb + (long)r * ED + c * 4, Abuf + chunk * 1024);
        }
    };
    auto stageB = [&](int buf, int ks) {
        char* Bbuf = lds + 32 * 1024 + buf * 24 * 1024;
        const unsigned short* wb = W1p + (size_t)ks * 12288;
        #pragma unroll
        for (int j = 0; j < 6; ++j) {
            int chunk = j * 4 + w;
            gl_lds16(wb + chunk * 512 + lane * 8, Bbuf + chunk * 1024);
        }
    };

    stageA(0, 0); stageB(0, 0);
    __syncthreads();

    int cur = 0;
    for (int ks = 0; ks < 16; ++ks) {
        if (ks < 15) { stageA(cur ^ 1, ks + 1); stageB(cur ^ 1, ks + 1); }
        char* Ac = lds + cur * 16 * 1024;
        char* Bc = lds + 32 * 1024 + cur * 24 * 1024;
        const int r = w * 16 + lr;
        #pragma unroll
        for (int kh = 0; kh < 2; ++kh) {
            // A fragment: 8 fp32 at k = kh*32 + lg*8, swizzled 16B blocks
            int cb0 = kh * 8 + lg * 2;
            float4 fa = *(const float4*)(Ac + r * 256 + ((cb0 ^ (r & 7)) * 16));
            float4 fb = *(const float4*)(Ac + r * 256 + (((cb0 + 1) ^ (r & 7)) * 16));
            bf16x8 a;
            a[0] = (short)f2bf(fa.x); a[1] = (short)f2bf(fa.y);
            a[2] = (short)f2bf(fa.z); a[3] = (short)f2bf(fa.w);
            a[4] = (short)f2bf(fb.x); a[5] = (short)f2bf(fb.y);
            a[6] = (short)f2bf(fb.z); a[7] = (short)f2bf(fb.w);
            #pragma unroll
            for (int n = 0; n < 12; ++n) {
                bf16x8 bv = *(const bf16x8*)(Bc + swz(n * 16 + lr, kh * 64 + lg * 16));
                acc[n] = __builtin_amdgcn_mfma_f32_16x16x32_bf16(a, bv, acc[n], 0, 0, 0);
            }
        }
        __syncthreads();   // drains prefetch (vmcnt) + all LDS reads
        cur ^= 1;
    }

    // ---- epilogue: fused second layers + V transpose ----
    char* H  = lds + w * 2048;       // per-wave [16][128B]
    char* VT = lds + 16 * 1024;      // [64 h][128B = 64 t bf16]

    #pragma unroll
    for (int kq = 0; kq < 2; ++kq) {
        const float* b1 = kq ? qb1 : kb1;
        const float* b2 = kq ? qb2 : kb2;
        unsigned short* dst = kq ? Qo : Ko;
        #pragma unroll
        for (int n = 0; n < 4; ++n) {
            int col = n * 16 + lr;
            float bias = b1[col];
            #pragma unroll
            for (int rr = 0; rr < 4; ++rr) {
                int row = lg * 4 + rr;
                *(unsigned short*)(H + swz(row, col * 2)) =
                    f2bf(fmaxf(acc[kq * 4 + n][rr] + bias, 0.f));
            }
        }
        f32x4 acc2[4];
        #pragma unroll
        for (int n = 0; n < 4; ++n) acc2[n] = fzero4();
        #pragma unroll
        for (int kh = 0; kh < 2; ++kh) {
            bf16x8 a2 = *(const bf16x8*)(H + swz(lr, kh * 64 + lg * 16));
            #pragma unroll
            for (int n = 0; n < 4; ++n) {
                bf16x8 w2f = *(const bf16x8*)(W2p + ((kq * 4 + n) * 2 + kh) * 512 + lane * 8);
                acc2[n] = __builtin_amdgcn_mfma_f32_16x16x32_bf16(a2, w2f, acc2[n], 0, 0, 0);
            }
        }
        #pragma unroll
        for (int n = 0; n < 4; ++n) {
            int col = n * 16 + lr;
            float bias = b2[col];
            #pragma unroll
            for (int rr = 0; rr < 4; ++rr) {
                long rg = r0 + w * 16 + lg * 4 + rr;
                dst[rg * KD + col] = f2bf(fmaxf(acc2[n][rr] + bias, 0.f));
            }
        }
    }

    // values -> VT (transposed in LDS) -> coalesced global store
    #pragma unroll
    for (int n = 0; n < 4; ++n) {
        int col = n * 16 + lr;        // h
        float bias = vb[col];
        #pragma unroll
        for (int rr = 0; rr < 4; ++rr) {
            int tl = w * 16 + lg * 4 + rr;   // t_local 0..63
            *(unsigned short*)(VT + swz(col, tl * 2)) = f2bf(acc[8 + n][rr] + bias);
        }
    }
    __syncthreads();
    #pragma unroll
    for (int it = 0; it < 2; ++it) {
        int c = it * 256 + tid;
        int h = c >> 3, c4 = c & 7;          // 8 int4 per 128B row
        *(int4*)(Vt + ((long)b * KD + h) * TCTX + tb + c4 * 8) =
            *(const int4*)(VT + swz(h, c4 * 16));
    }
}

// ---------------------------------------------------------------------------
// Flash attention with the reference's exact mask semantics:
// masked (s<=t) entries get score = -1e10f (matches fp32 `score + -1e10`).
// QB=64 q-rows/block (4 waves x 16 rows), online softmax in fp32.
// Last q-tile sweeps all s-tiles (row 4095 fully masked -> uniform softmax).
// V consumed from Vt[b][h][t] so the PV B-operand reads rows of [h][s].
// ---------------------------------------------------------------------------
__global__ __launch_bounds__(256) void attn_kernel(
    const unsigned short* __restrict__ Qb,
    const unsigned short* __restrict__ Kb,
    const unsigned short* __restrict__ Vt,
    float* __restrict__ out)
{
    __shared__ __align__(16) char lds[32 * 1024];
    char* Qs = lds;                // [64 q][128B]
    char* Ks = lds + 8 * 1024;     // [64 s][128B]
    char* Vs = lds + 16 * 1024;    // [64 h][128B]  (rows = h, cols = s)
    char* Ps = lds + 24 * 1024;    // 4 x [16][128B] per-wave P tiles

    const int bid = blockIdx.x;
    const int b   = bid & 7;
    const int qr  = bid >> 3;
    const int qi  = (qr + 63) & 63;   // rotate so the heavy full-sweep tile launches first
    const int t0  = qi * 64;
    const int tid = threadIdx.x, lane = tid & 63, w = tid >> 6;
    const int lr  = lane & 15, lg = lane >> 4;

    // stage Q tile once
    const unsigned short* Qg = Qb + ((long)b * TCTX + t0) * KD;
    #pragma unroll
    for (int it = 0; it < 2; ++it) {
        int c = it * 256 + tid;
        int row = c >> 3, cb = c & 7;
        *(int4*)(Qs + swz(row, cb * 16)) = *(const int4*)(Qg + row * KD + cb * 8);
    }

    float m_[4], sum_[4];
    f32x4 O[4];
    #pragma unroll
    for (int rr = 0; rr < 4; ++rr) { m_[rr] = -INFINITY; sum_[rr] = 0.f; }
    #pragma unroll
    for (int n = 0; n < 4; ++n) O[n] = fzero4();

    const int s_begin = (qi == 63) ? 0 : qi;
    for (int si = s_begin; si < 64; ++si) {
        const int s0 = si * 64;
        __syncthreads();
        const unsigned short* Kg = Kb + ((long)b * TCTX + s0) * KD;
        const unsigned short* Vg = Vt + (long)b * KD * TCTX + s0;
        #pragma unroll
        for (int it = 0; it < 2; ++it) {
            int c = it * 256 + tid;
            int row = c >> 3, cb = c & 7;
            *(int4*)(Ks + swz(row, cb * 16)) = *(const int4*)(Kg + row * KD + cb * 8);
            *(int4*)(Vs + swz(row, cb * 16)) = *(const int4*)(Vg + (long)row * TCTX + cb * 8);
        }
        __syncthreads();

        // QK^T: wave w handles q-rows w*16..w*16+15, all 64 s
        f32x4 sc[4];
        #pragma unroll
        for (int n = 0; n < 4; ++n) sc[n] = fzero4();
        #pragma unroll
        for (int kh = 0; kh < 2; ++kh) {
            bf16x8 a = *(bf16x8*)(Qs + swz(w * 16 + lr, kh * 64 + lg * 16));
            #pragma unroll
            for (int n = 0; n < 4; ++n) {
                bf16x8 bk = *(bf16x8*)(Ks + swz(n * 16 + lr, kh * 64 + lg * 16));
                sc[n] = __builtin_amdgcn_mfma_f32_16x16x32_bf16(a, bk, sc[n], 0, 0, 0);
            }
        }

        // masked scores (faithful fp32 semantics)
        float p[4][4];   // [n][rr]
        #pragma unroll
        for (int n = 0; n < 4; ++n) {
            int sg = s0 + n * 16 + lr;
            #pragma unroll
            for (int rr = 0; rr < 4; ++rr) {
                int tg = t0 + w * 16 + lg * 4 + rr;
                float v = sc[n][rr] * 0.125f;
                if (sg <= tg) v = -1e10f;
                p[n][rr] = v;
            }
        }
        // online softmax per q-row (16-lane groups share a row set)
        #pragma unroll
        for (int rr = 0; rr < 4; ++rr) {
            float mx = fmaxf(fmaxf(p[0][rr], p[1][rr]), fmaxf(p[2][rr], p[3][rr]));
            #pragma unroll
            for (int d = 1; d < 16; d <<= 1) mx = fmaxf(mx, __shfl_xor(mx, d, 64));
            float mn = fmaxf(m_[rr], mx);
            float scl = __expf(m_[rr] - mn);
            m_[rr] = mn;
            float ls = 0.f;
            #pragma unroll
            for (int n = 0; n < 4; ++n) { p[n][rr] = __expf(p[n][rr] - mn); ls += p[n][rr]; }
            #pragma unroll
            for (int d = 1; d < 16; d <<= 1) ls += __shfl_xor(ls, d, 64);
            sum_[rr] = sum_[rr] * scl + ls;
            #pragma unroll
            for (int n = 0; n < 4; ++n) O[n][rr] *= scl;
        }

        // P -> LDS (bf16), per-wave private region
        char* Pw = Ps + w * 2048;
        #pragma unroll
        for (int n = 0; n < 4; ++n) {
            int col = n * 16 + lr;
            #pragma unroll
            for (int rr = 0; rr < 4; ++rr) {
                int row = lg * 4 + rr;
                *(unsigned short*)(Pw + swz(row, col * 2)) = f2bf(p[n][rr]);
            }
        }
        // PV: O += P @ V   (B-operand = rows of Vs = [h][s] -> lane c holds V[s][h=c])
        #pragma unroll
        for (int kh = 0; kh < 2; ++kh) {
            bf16x8 ap = *(bf16x8*)(Pw + swz(lr, kh * 64 + lg * 16));
            #pragma unroll
            for (int n = 0; n < 4; ++n) {
                bf16x8 bv = *(bf16x8*)(Vs + swz(n * 16 + lr, kh * 64 + lg * 16));
                O[n] = __builtin_amdgcn_mfma_f32_16x16x32_bf16(ap, bv, O[n], 0, 0, 0);
            }
        }
    }

    // epilogue: out = O / sum
    #pragma unroll
    for (int n = 0; n < 4; ++n) {
        int col = n * 16 + lr;
        #pragma unroll
        for (int rr = 0; rr < 4; ++rr) {
            int tg = t0 + w * 16 + lg * 4 + rr;
            out[((long)b * TCTX + tg) * KD + col] = O[n][rr] / sum_[rr];
        }
    }
}

extern "C" void kernel_launch(void* const* d_in, const int* in_sizes, int n_in,
                              void* d_out, int out_size, void* d_ws, size_t ws_size,
                              hipStream_t stream) {
    const float* emb = (const float*)d_in[0];
    const float* kw1 = (const float*)d_in[1];
    const float* kb1 = (const float*)d_in[2];
    const float* kw2 = (const float*)d_in[3];
    const float* kb2 = (const float*)d_in[4];
    const float* qw1 = (const float*)d_in[5];
    const float* qb1 = (const float*)d_in[6];
    const float* qw2 = (const float*)d_in[7];
    const float* qb2 = (const float*)d_in[8];
    const float* vw  = (const float*)d_in[9];
    const float* vb  = (const float*)d_in[10];

    unsigned short* Qb  = (unsigned short*)d_ws;               // 4 MB
    unsigned short* Kb  = Qb + (size_t)NB * TCTX * KD;         // 4 MB
    unsigned short* Vt  = Kb + (size_t)NB * TCTX * KD;         // 4 MB, [b][h][t]
    unsigned short* W1p = Vt + (size_t)NB * TCTX * KD;         // 384 KB
    unsigned short* W2p = W1p + 196608;                        // 16 KB

    hipLaunchKernelGGL(prep_kernel, dim3(100), dim3(256), 0, stream,
                       kw1, qw1, vw, kw2, qw2, W1p, W2p);
    hipLaunchKernelGGL(proj_kernel, dim3(512), dim3(256), 0, stream,
                       emb, W1p, W2p, kb1, kb2, qb1, qb2, vb,
                       Qb, Kb, Vt);
    hipLaunchKernelGGL(attn_kernel, dim3(512), dim3(256), 0, stream,
                       Qb, Kb, Vt, (float*)d_out);
}

// Round 6
// 108.909 us; speedup vs baseline: 2.1430x; 1.3635x over previous
//
#include <hip/hip_runtime.h>
#include <hip/hip_bf16.h>
#include <math.h>

// Problem constants
#define NB   8
#define TCTX 4096
#define ED   1024
#define KD   64

typedef __attribute__((ext_vector_type(8))) short bf16x8;
typedef __attribute__((ext_vector_type(4))) float f32x4;

#define LOG2E  1.44269504088896340736f
#define SCALE2 (0.125f * LOG2E)          // score*0.125 folded into log2 domain
#define MASK2  (-1e10f * LOG2E)          // -1e10 in log2 domain

__device__ __forceinline__ unsigned short f2bf(float f) {
    union { float f; unsigned u; } c; c.f = f;
    return (unsigned short)((c.u + 0x7FFFu + ((c.u >> 16) & 1u)) >> 16);
}
// LDS tiles with 128-byte rows; XOR-swizzle 16B blocks to kill bank conflicts.
__device__ __forceinline__ int swz(int row, int byteoff) {
    return row * 128 + (byteoff ^ ((row & 7) << 4));
}
__device__ __forceinline__ f32x4 fzero4() {
    f32x4 z; z[0] = 0.f; z[1] = 0.f; z[2] = 0.f; z[3] = 0.f; return z;
}
// async global->LDS, 16B per lane; LDS dest = wave-uniform base + lane*16
__device__ __forceinline__ void gl_lds16(const void* g, void* l) {
    __builtin_amdgcn_global_load_lds(
        (const __attribute__((address_space(1))) unsigned int*)g,
        (__attribute__((address_space(3))) unsigned int*)l, 16, 0, 0);
}
__device__ __forceinline__ unsigned cvtpk_bf16(float lo, float hi) {
    unsigned r;
    asm("v_cvt_pk_bf16_f32 %0, %1, %2" : "=v"(r) : "v"(lo), "v"(hi));
    return r;
}

// ---------------------------------------------------------------------------
// Prep kernel: one-time weight repack (fp32 -> bf16).
// ---------------------------------------------------------------------------
__global__ __launch_bounds__(256) void prep_kernel(
    const float* __restrict__ kw1, const float* __restrict__ qw1,
    const float* __restrict__ vw,  const float* __restrict__ kw2,
    const float* __restrict__ qw2,
    unsigned short* __restrict__ W1p, unsigned short* __restrict__ W2p)
{
    int idx = blockIdx.x * 256 + threadIdx.x;   // 16B-block index
    if (idx < 24576) {
        int ks = idx / 1536, rem = idx % 1536;
        int r = rem >> 3, bb = rem & 7;
        int c = bb ^ (r & 7);
        const float* src = (r < 64)  ? (kw1 + r * ED)
                         : (r < 128) ? (qw1 + (r - 64) * ED)
                                     : (vw  + (r - 128) * ED);
        src += ks * 64 + c * 8;
        unsigned short* dst = W1p + (size_t)idx * 8;
        #pragma unroll
        for (int e = 0; e < 8; ++e) dst[e] = f2bf(src[e]);
    } else if (idx < 25600) {
        int j = idx - 24576;
        int lane = j & 63, kh = (j >> 6) & 1, n = (j >> 7) & 3, kq = j >> 9;
        int row = n * 16 + (lane & 15);
        int ko  = kh * 32 + (lane >> 4) * 8;
        const float* src = (kq ? qw2 : kw2) + row * 64 + ko;
        unsigned short* dst = W2p + (size_t)j * 8;
        #pragma unroll
        for (int e = 0; e < 8; ++e) dst[e] = f2bf(src[e]);
    }
}

// ---------------------------------------------------------------------------
// Projection kernel, async-staged + double-buffered (unchanged from R4).
// ---------------------------------------------------------------------------
__global__ __launch_bounds__(256, 2) void proj_kernel(
    const float* __restrict__ emb,
    const unsigned short* __restrict__ W1p, const unsigned short* __restrict__ W2p,
    const float* __restrict__ kb1, const float* __restrict__ kb2,
    const float* __restrict__ qb1, const float* __restrict__ qb2,
    const float* __restrict__ vb,
    unsigned short* __restrict__ Qo, unsigned short* __restrict__ Ko,
    unsigned short* __restrict__ Vt)
{
    __shared__ __align__(16) char lds[80 * 1024];
    // A buffers at 0 / 16KB (fp32 [64][256B]); B buffers at 32KB / 56KB (bf16 [192][128B])

    const int tid  = threadIdx.x;
    const int lane = tid & 63;
    const int w    = tid >> 6;
    const int lr   = lane & 15;
    const int lg   = lane >> 4;
    const long r0  = (long)blockIdx.x * 64;
    const int  b   = blockIdx.x >> 6;            // 64 blocks per batch
    const int  tb  = (blockIdx.x & 63) * 64;     // t base within batch

    const float* embB = emb + r0 * ED;

    f32x4 acc[12];
    #pragma unroll
    for (int j = 0; j < 12; ++j) acc[j] = fzero4();

    auto stageA = [&](int buf, int ks) {
        char* Abuf = lds + buf * 16 * 1024;
        const float* eb = embB + ks * 64;
        #pragma unroll
        for (int j = 0; j < 4; ++j) {
            int chunk = j * 4 + w;                    // 1KB chunks (256B rows)
            int r = chunk * 4 + (lane >> 4);          // 4 rows per chunk
            int c = (lane & 15) ^ (r & 7);            // pre-swizzled source
            gl_lds16(eb + (long)r * ED + c * 4, Abuf + chunk * 1024);
        }
    };
    auto stageB = [&](int buf, int ks) {
        char* Bbuf = lds + 32 * 1024 + buf * 24 * 1024;
        const unsigned short* wb = W1p + (size_t)ks * 12288;
        #pragma unroll
        for (int j = 0; j < 6; ++j) {
            int chunk = j * 4 + w;
            gl_lds16(wb + chunk * 512 + lane * 8, Bbuf + chunk * 1024);
        }
    };

    stageA(0, 0); stageB(0, 0);
    __syncthreads();

    int cur = 0;
    for (int ks = 0; ks < 16; ++ks) {
        if (ks < 15) { stageA(cur ^ 1, ks + 1); stageB(cur ^ 1, ks + 1); }
        char* Ac = lds + cur * 16 * 1024;
        char* Bc = lds + 32 * 1024 + cur * 24 * 1024;
        const int r = w * 16 + lr;
        #pragma unroll
        for (int kh = 0; kh < 2; ++kh) {
            int cb0 = kh * 8 + lg * 2;
            float4 fa = *(const float4*)(Ac + r * 256 + ((cb0 ^ (r & 7)) * 16));
            float4 fb = *(const float4*)(Ac + r * 256 + (((cb0 + 1) ^ (r & 7)) * 16));
            bf16x8 a;
            a[0] = (short)f2bf(fa.x); a[1] = (short)f2bf(fa.y);
            a[2] = (short)f2bf(fa.z); a[3] = (short)f2bf(fa.w);
            a[4] = (short)f2bf(fb.x); a[5] = (short)f2bf(fb.y);
            a[6] = (short)f2bf(fb.z); a[7] = (short)f2bf(fb.w);
            #pragma unroll
            for (int n = 0; n < 12; ++n) {
                bf16x8 bv = *(const bf16x8*)(Bc + swz(n * 16 + lr, kh * 64 + lg * 16));
                acc[n] = __builtin_amdgcn_mfma_f32_16x16x32_bf16(a, bv, acc[n], 0, 0, 0);
            }
        }
        __syncthreads();
        cur ^= 1;
    }

    // ---- epilogue: fused second layers + V transpose ----
    char* H  = lds + w * 2048;       // per-wave [16][128B]
    char* VT = lds + 16 * 1024;      // [64 h][128B = 64 t bf16]

    #pragma unroll
    for (int kq = 0; kq < 2; ++kq) {
        const float* b1 = kq ? qb1 : kb1;
        const float* b2 = kq ? qb2 : kb2;
        unsigned short* dst = kq ? Qo : Ko;
        #pragma unroll
        for (int n = 0; n < 4; ++n) {
            int col = n * 16 + lr;
            float bias = b1[col];
            #pragma unroll
            for (int rr = 0; rr < 4; ++rr) {
                int row = lg * 4 + rr;
                *(unsigned short*)(H + swz(row, col * 2)) =
                    f2bf(fmaxf(acc[kq * 4 + n][rr] + bias, 0.f));
            }
        }
        f32x4 acc2[4];
        #pragma unroll
        for (int n = 0; n < 4; ++n) acc2[n] = fzero4();
        #pragma unroll
        for (int kh = 0; kh < 2; ++kh) {
            bf16x8 a2 = *(const bf16x8*)(H + swz(lr, kh * 64 + lg * 16));
            #pragma unroll
            for (int n = 0; n < 4; ++n) {
                bf16x8 w2f = *(const bf16x8*)(W2p + ((kq * 4 + n) * 2 + kh) * 512 + lane * 8);
                acc2[n] = __builtin_amdgcn_mfma_f32_16x16x32_bf16(a2, w2f, acc2[n], 0, 0, 0);
            }
        }
        #pragma unroll
        for (int n = 0; n < 4; ++n) {
            int col = n * 16 + lr;
            float bias = b2[col];
            #pragma unroll
            for (int rr = 0; rr < 4; ++rr) {
                long rg = r0 + w * 16 + lg * 4 + rr;
                dst[rg * KD + col] = f2bf(fmaxf(acc2[n][rr] + bias, 0.f));
            }
        }
    }

    #pragma unroll
    for (int n = 0; n < 4; ++n) {
        int col = n * 16 + lr;        // h
        float bias = vb[col];
        #pragma unroll
        for (int rr = 0; rr < 4; ++rr) {
            int tl = w * 16 + lg * 4 + rr;   // t_local 0..63
            *(unsigned short*)(VT + swz(col, tl * 2)) = f2bf(acc[8 + n][rr] + bias);
        }
    }
    __syncthreads();
    #pragma unroll
    for (int it = 0; it < 2; ++it) {
        int c = it * 256 + tid;
        int h = c >> 3, c4 = c & 7;          // 8 int4 per 128B row
        *(int4*)(Vt + ((long)b * KD + h) * TCTX + tb + c4 * 8) =
            *(const int4*)(VT + swz(h, c4 * 16));
    }
}

// ---------------------------------------------------------------------------
// Flash attention, swapped-QK^T structure.
// QK: mfma(A=K, B=Q) -> C[s][t]: each lane owns ONE q-row t=lr; 16 s-values
//   in-register -> softmax = in-lane reduce + 2 shfl_xor + 4 broadcasts.
// K/V/Q staged via global_load_lds, 128B rows: 1KB chunk = 8 rows;
//   lane -> row chunk*8 + (lane>>3), logical block (lane&7) ^ (row&7)
//   (pre-swizzled source, linear LDS dest).  [R5 bug: used 256B-row mapping]
// Double-buffered K/V, ONE barrier per tile. qi==63: P=1 fast path for
//   fully-masked tiles (bit-identical to generic path).
// ---------------------------------------------------------------------------
__global__ __launch_bounds__(256) void attn_kernel(
    const unsigned short* __restrict__ Qb,
    const unsigned short* __restrict__ Kb,
    const unsigned short* __restrict__ Vt,
    float* __restrict__ out)
{
    __shared__ __align__(16) char lds[40 * 1024];
    // buf b: K at b*16KB, V at b*16KB+8KB ; Q/P region at 32KB (8KB)

    const int bid = blockIdx.x;
    const int b   = bid & 7;
    const int qr  = bid >> 3;
    const int qi  = (qr + 63) & 63;   // heavy tiles launch first
    const int t0  = qi * 64;
    const int tid = threadIdx.x, lane = tid & 63, w = tid >> 6;
    const int lr  = lane & 15, lg = lane >> 4;
    const int tg  = t0 + w * 16 + lr;      // this lane's q-row (softmax owner)

    char* QP = lds + 32 * 1024;            // Q rows / per-wave P tiles

    const unsigned short* Qg  = Qb + ((long)b * TCTX + t0) * KD;
    const unsigned short* Kg0 = Kb + (long)b * TCTX * KD;
    const unsigned short* Vg0 = Vt + (long)b * KD * TCTX;

    // 128B-row staging mapping: row = chunk*8 + (lane>>3), block = lane&7
    const int srow = lane >> 3;
    const int sblk = lane & 7;

    // stage Q (8KB) via async DMA, pre-swizzled source
    #pragma unroll
    for (int j = 0; j < 2; ++j) {
        int chunk = j * 4 + w;
        int r = chunk * 8 + srow;
        int c = sblk ^ (r & 7);
        gl_lds16(Qg + r * KD + c * 8, QP + chunk * 1024);
    }

    auto stageKV = [&](int buf, int si) {
        char* Kl = lds + buf * 16 * 1024;
        char* Vl = Kl + 8 * 1024;
        const unsigned short* Kg = Kg0 + si * 64 * KD;
        const unsigned short* Vg = Vg0 + si * 64;
        #pragma unroll
        for (int j = 0; j < 2; ++j) {
            int chunk = j * 4 + w;
            int r = chunk * 8 + srow;
            int c = sblk ^ (r & 7);
            gl_lds16(Kg + r * KD + c * 8, Kl + chunk * 1024);
            gl_lds16(Vg + (long)r * TCTX + c * 8, Vl + chunk * 1024);
        }
    };

    const int s_begin = (qi == 63) ? 0 : qi;
    stageKV(0, s_begin);
    __syncthreads();                       // drains vmcnt: Q + buf0 ready

    // hoist Q fragments (B-operand: lane c=lr holds Q[t=w*16+c][k])
    bf16x8 qf[2];
    #pragma unroll
    for (int kh = 0; kh < 2; ++kh)
        qf[kh] = *(const bf16x8*)(QP + swz(w * 16 + lr, kh * 64 + lg * 16));

    // ones-P for the fully-masked tiles of qi==63 (after qf hoist; wave-private)
    if (qi == 63) {
        uint2 ones = make_uint2(0x3F803F80u, 0x3F803F80u);
        #pragma unroll
        for (int n = 0; n < 4; ++n)
            *(uint2*)(QP + swz(w * 16 + lr, n * 32 + lg * 8)) = ones;
    }

    float m2 = MASK2, sum_ = 0.f;
    f32x4 O[4];
    #pragma unroll
    for (int n = 0; n < 4; ++n) O[n] = fzero4();

    int cur = 0;
    for (int si = s_begin; si < 64; ++si) {
        if (si < 63) stageKV(cur ^ 1, si + 1);
        char* Kl = lds + cur * 16 * 1024;
        char* Vl = Kl + 8 * 1024;

        if (!((qi == 63) && (si < 63))) {
            // ---- QK^T (swapped): C[s][t], t = lr per lane ----
            f32x4 sc[4];
            #pragma unroll
            for (int n = 0; n < 4; ++n) sc[n] = fzero4();
            #pragma unroll
            for (int kh = 0; kh < 2; ++kh) {
                #pragma unroll
                for (int n = 0; n < 4; ++n) {
                    bf16x8 kf = *(const bf16x8*)(Kl + swz(n * 16 + lr, kh * 64 + lg * 16));
                    sc[n] = __builtin_amdgcn_mfma_f32_16x16x32_bf16(kf, qf[kh], sc[n], 0, 0, 0);
                }
            }
            // ---- masked scores in exp2 domain ----
            const int thr = tg - si * 64;   // mask if s_local <= thr
            float s2v[4][4];
            #pragma unroll
            for (int n = 0; n < 4; ++n)
                #pragma unroll
                for (int rr = 0; rr < 4; ++rr) {
                    int sl = n * 16 + lg * 4 + rr;
                    float v = sc[n][rr] * SCALE2;
                    s2v[n][rr] = (sl <= thr) ? MASK2 : v;
                }
            // ---- online softmax: in-lane reduce + 2-level shfl ----
            float pm = s2v[0][0];
            #pragma unroll
            for (int n = 0; n < 4; ++n)
                #pragma unroll
                for (int rr = 0; rr < 4; ++rr) pm = fmaxf(pm, s2v[n][rr]);
            pm = fmaxf(pm, __shfl_xor(pm, 16, 64));
            pm = fmaxf(pm, __shfl_xor(pm, 32, 64));
            float mnew = fmaxf(m2, pm);
            float scl = __builtin_amdgcn_exp2f(m2 - mnew);
            m2 = mnew;
            float ls = 0.f;
            #pragma unroll
            for (int n = 0; n < 4; ++n)
                #pragma unroll
                for (int rr = 0; rr < 4; ++rr) {
                    s2v[n][rr] = __builtin_amdgcn_exp2f(s2v[n][rr] - mnew);
                    ls += s2v[n][rr];
                }
            ls += __shfl_xor(ls, 16, 64);
            ls += __shfl_xor(ls, 32, 64);
            sum_ = sum_ * scl + ls;
            // broadcast scl to O-row owners (O rows t_local = lg*4+rr)
            #pragma unroll
            for (int rr = 0; rr < 4; ++rr) {
                float sb = __shfl(scl, lg * 4 + rr, 64);
                #pragma unroll
                for (int n = 0; n < 4; ++n) O[n][rr] *= sb;
            }
            // ---- pack P (bf16 pairs) -> per-wave LDS region ----
            #pragma unroll
            for (int n = 0; n < 4; ++n) {
                unsigned lo = cvtpk_bf16(s2v[n][0], s2v[n][1]);
                unsigned hi = cvtpk_bf16(s2v[n][2], s2v[n][3]);
                *(uint2*)(QP + swz(w * 16 + lr, n * 32 + lg * 8)) = make_uint2(lo, hi);
            }
        } else {
            sum_ += 64.f;                   // P==1, m stays MASK2
        }

        // ---- PV: O += P @ V ----
        #pragma unroll
        for (int kh = 0; kh < 2; ++kh) {
            bf16x8 ap = *(const bf16x8*)(QP + swz(w * 16 + lr, kh * 64 + lg * 16));
            #pragma unroll
            for (int n = 0; n < 4; ++n) {
                bf16x8 bv = *(const bf16x8*)(Vl + swz(n * 16 + lr, kh * 64 + lg * 16));
                O[n] = __builtin_amdgcn_mfma_f32_16x16x32_bf16(ap, bv, O[n], 0, 0, 0);
            }
        }
        __syncthreads();                    // drains next-tile DMA; frees cur
        cur ^= 1;
    }

    // ---- epilogue: out = O / sum (sum broadcast from row-owner lanes) ----
    #pragma unroll
    for (int rr = 0; rr < 4; ++rr) {
        float sb = __shfl(sum_, lg * 4 + rr, 64);
        int t = t0 + w * 16 + lg * 4 + rr;
        #pragma unroll
        for (int n = 0; n < 4; ++n)
            out[((long)b * TCTX + t) * KD + n * 16 + lr] = O[n][rr] / sb;
    }
}

extern "C" void kernel_launch(void* const* d_in, const int* in_sizes, int n_in,
                              void* d_out, int out_size, void* d_ws, size_t ws_size,
                              hipStream_t stream) {
    const float* emb = (const float*)d_in[0];
    const float* kw1 = (const float*)d_in[1];
    const float* kb1 = (const float*)d_in[2];
    const float* kw2 = (const float*)d_in[3];
    const float* kb2 = (const float*)d_in[4];
    const float* qw1 = (const float*)d_in[5];
    const float* qb1 = (const float*)d_in[6];
    const float* qw2 = (const float*)d_in[7];
    const float* qb2 = (const float*)d_in[8];
    const float* vw  = (const float*)d_in[9];
    const float* vb  = (const float*)d_in[10];

    unsigned short* Qb  = (unsigned short*)d_ws;               // 4 MB
    unsigned short* Kb  = Qb + (size_t)NB * TCTX * KD;         // 4 MB
    unsigned short* Vt  = Kb + (size_t)NB * TCTX * KD;         // 4 MB, [b][h][t]
    unsigned short* W1p = Vt + (size_t)NB * TCTX * KD;         // 384 KB
    unsigned short* W2p = W1p + 196608;                        // 16 KB

    hipLaunchKernelGGL(prep_kernel, dim3(100), dim3(256), 0, stream,
                       kw1, qw1, vw, kw2, qw2, W1p, W2p);
    hipLaunchKernelGGL(proj_kernel, dim3(512), dim3(256), 0, stream,
                       emb, W1p, W2p, kb1, kb2, qb1, qb2, vb,
                       Qb, Kb, Vt);
    hipLaunchKernelGGL(attn_kernel, dim3(512), dim3(256), 0, stream,
                       Qb, Kb, Vt, (float*)d_out);
}

// Round 7
// 102.350 us; speedup vs baseline: 2.2803x; 1.0641x over previous
//
#include <hip/hip_runtime.h>
#include <hip/hip_bf16.h>
#include <math.h>

// Problem constants
#define NB   8
#define TCTX 4096
#define ED   1024
#define KD   64

typedef __attribute__((ext_vector_type(8))) short bf16x8;
typedef __attribute__((ext_vector_type(4))) float f32x4;

#define LOG2E  1.44269504088896340736f
#define SCALE2 (0.125f * LOG2E)          // score*0.125 folded into log2 domain
#define MASK2  (-1e10f * LOG2E)          // -1e10 in log2 domain

__device__ __forceinline__ unsigned short f2bf(float f) {
    union { float f; unsigned u; } c; c.f = f;
    return (unsigned short)((c.u + 0x7FFFu + ((c.u >> 16) & 1u)) >> 16);
}
// LDS tiles with 128-byte rows; XOR-swizzle 16B blocks to kill bank conflicts.
__device__ __forceinline__ int swz(int row, int byteoff) {
    return row * 128 + (byteoff ^ ((row & 7) << 4));
}
__device__ __forceinline__ f32x4 fzero4() {
    f32x4 z; z[0] = 0.f; z[1] = 0.f; z[2] = 0.f; z[3] = 0.f; return z;
}
// async global->LDS, 16B per lane; LDS dest = wave-uniform base + lane*16
__device__ __forceinline__ void gl_lds16(const void* g, void* l) {
    __builtin_amdgcn_global_load_lds(
        (const __attribute__((address_space(1))) unsigned int*)g,
        (__attribute__((address_space(3))) unsigned int*)l, 16, 0, 0);
}
__device__ __forceinline__ unsigned cvtpk_bf16(float lo, float hi) {
    unsigned r;
    asm("v_cvt_pk_bf16_f32 %0, %1, %2" : "=v"(r) : "v"(lo), "v"(hi));
    return r;
}

// ---------------------------------------------------------------------------
// Prep kernel: one-time weight repack (fp32 -> bf16).  (unchanged)
// ---------------------------------------------------------------------------
__global__ __launch_bounds__(256) void prep_kernel(
    const float* __restrict__ kw1, const float* __restrict__ qw1,
    const float* __restrict__ vw,  const float* __restrict__ kw2,
    const float* __restrict__ qw2,
    unsigned short* __restrict__ W1p, unsigned short* __restrict__ W2p)
{
    int idx = blockIdx.x * 256 + threadIdx.x;   // 16B-block index
    if (idx < 24576) {
        int ks = idx / 1536, rem = idx % 1536;
        int r = rem >> 3, bb = rem & 7;
        int c = bb ^ (r & 7);
        const float* src = (r < 64)  ? (kw1 + r * ED)
                         : (r < 128) ? (qw1 + (r - 64) * ED)
                                     : (vw  + (r - 128) * ED);
        src += ks * 64 + c * 8;
        unsigned short* dst = W1p + (size_t)idx * 8;
        #pragma unroll
        for (int e = 0; e < 8; ++e) dst[e] = f2bf(src[e]);
    } else if (idx < 25600) {
        int j = idx - 24576;
        int lane = j & 63, kh = (j >> 6) & 1, n = (j >> 7) & 3, kq = j >> 9;
        int row = n * 16 + (lane & 15);
        int ko  = kh * 32 + (lane >> 4) * 8;
        const float* src = (kq ? qw2 : kw2) + row * 64 + ko;
        unsigned short* dst = W2p + (size_t)j * 8;
        #pragma unroll
        for (int e = 0; e < 8; ++e) dst[e] = f2bf(src[e]);
    }
}

// ---------------------------------------------------------------------------
// Projection kernel, async-staged + double-buffered (unchanged from R6).
// ---------------------------------------------------------------------------
__global__ __launch_bounds__(256, 2) void proj_kernel(
    const float* __restrict__ emb,
    const unsigned short* __restrict__ W1p, const unsigned short* __restrict__ W2p,
    const float* __restrict__ kb1, const float* __restrict__ kb2,
    const float* __restrict__ qb1, const float* __restrict__ qb2,
    const float* __restrict__ vb,
    unsigned short* __restrict__ Qo, unsigned short* __restrict__ Ko,
    unsigned short* __restrict__ Vt)
{
    __shared__ __align__(16) char lds[80 * 1024];
    // A buffers at 0 / 16KB (fp32 [64][256B]); B buffers at 32KB / 56KB (bf16 [192][128B])

    const int tid  = threadIdx.x;
    const int lane = tid & 63;
    const int w    = tid >> 6;
    const int lr   = lane & 15;
    const int lg   = lane >> 4;
    const long r0  = (long)blockIdx.x * 64;
    const int  b   = blockIdx.x >> 6;            // 64 blocks per batch
    const int  tb  = (blockIdx.x & 63) * 64;     // t base within batch

    const float* embB = emb + r0 * ED;

    f32x4 acc[12];
    #pragma unroll
    for (int j = 0; j < 12; ++j) acc[j] = fzero4();

    auto stageA = [&](int buf, int ks) {
        char* Abuf = lds + buf * 16 * 1024;
        const float* eb = embB + ks * 64;
        #pragma unroll
        for (int j = 0; j < 4; ++j) {
            int chunk = j * 4 + w;                    // 1KB chunks (256B rows)
            int r = chunk * 4 + (lane >> 4);          // 4 rows per chunk
            int c = (lane & 15) ^ (r & 7);            // pre-swizzled source
            gl_lds16(eb + (long)r * ED + c * 4, Abuf + chunk * 1024);
        }
    };
    auto stageB = [&](int buf, int ks) {
        char* Bbuf = lds + 32 * 1024 + buf * 24 * 1024;
        const unsigned short* wb = W1p + (size_t)ks * 12288;
        #pragma unroll
        for (int j = 0; j < 6; ++j) {
            int chunk = j * 4 + w;
            gl_lds16(wb + chunk * 512 + lane * 8, Bbuf + chunk * 1024);
        }
    };

    stageA(0, 0); stageB(0, 0);
    __syncthreads();

    int cur = 0;
    for (int ks = 0; ks < 16; ++ks) {
        if (ks < 15) { stageA(cur ^ 1, ks + 1); stageB(cur ^ 1, ks + 1); }
        char* Ac = lds + cur * 16 * 1024;
        char* Bc = lds + 32 * 1024 + cur * 24 * 1024;
        const int r = w * 16 + lr;
        #pragma unroll
        for (int kh = 0; kh < 2; ++kh) {
            int cb0 = kh * 8 + lg * 2;
            float4 fa = *(const float4*)(Ac + r * 256 + ((cb0 ^ (r & 7)) * 16));
            float4 fb = *(const float4*)(Ac + r * 256 + (((cb0 + 1) ^ (r & 7)) * 16));
            bf16x8 a;
            a[0] = (short)f2bf(fa.x); a[1] = (short)f2bf(fa.y);
            a[2] = (short)f2bf(fa.z); a[3] = (short)f2bf(fa.w);
            a[4] = (short)f2bf(fb.x); a[5] = (short)f2bf(fb.y);
            a[6] = (short)f2bf(fb.z); a[7] = (short)f2bf(fb.w);
            #pragma unroll
            for (int n = 0; n < 12; ++n) {
                bf16x8 bv = *(const bf16x8*)(Bc + swz(n * 16 + lr, kh * 64 + lg * 16));
                acc[n] = __builtin_amdgcn_mfma_f32_16x16x32_bf16(a, bv, acc[n], 0, 0, 0);
            }
        }
        __syncthreads();
        cur ^= 1;
    }

    // ---- epilogue: fused second layers + V transpose ----
    char* H  = lds + w * 2048;       // per-wave [16][128B]
    char* VT = lds + 16 * 1024;      // [64 h][128B = 64 t bf16]

    #pragma unroll
    for (int kq = 0; kq < 2; ++kq) {
        const float* b1 = kq ? qb1 : kb1;
        const float* b2 = kq ? qb2 : kb2;
        unsigned short* dst = kq ? Qo : Ko;
        #pragma unroll
        for (int n = 0; n < 4; ++n) {
            int col = n * 16 + lr;
            float bias = b1[col];
            #pragma unroll
            for (int rr = 0; rr < 4; ++rr) {
                int row = lg * 4 + rr;
                *(unsigned short*)(H + swz(row, col * 2)) =
                    f2bf(fmaxf(acc[kq * 4 + n][rr] + bias, 0.f));
            }
        }
        f32x4 acc2[4];
        #pragma unroll
        for (int n = 0; n < 4; ++n) acc2[n] = fzero4();
        #pragma unroll
        for (int kh = 0; kh < 2; ++kh) {
            bf16x8 a2 = *(const bf16x8*)(H + swz(lr, kh * 64 + lg * 16));
            #pragma unroll
            for (int n = 0; n < 4; ++n) {
                bf16x8 w2f = *(const bf16x8*)(W2p + ((kq * 4 + n) * 2 + kh) * 512 + lane * 8);
                acc2[n] = __builtin_amdgcn_mfma_f32_16x16x32_bf16(a2, w2f, acc2[n], 0, 0, 0);
            }
        }
        #pragma unroll
        for (int n = 0; n < 4; ++n) {
            int col = n * 16 + lr;
            float bias = b2[col];
            #pragma unroll
            for (int rr = 0; rr < 4; ++rr) {
                long rg = r0 + w * 16 + lg * 4 + rr;
                dst[rg * KD + col] = f2bf(fmaxf(acc2[n][rr] + bias, 0.f));
            }
        }
    }

    #pragma unroll
    for (int n = 0; n < 4; ++n) {
        int col = n * 16 + lr;        // h
        float bias = vb[col];
        #pragma unroll
        for (int rr = 0; rr < 4; ++rr) {
            int tl = w * 16 + lg * 4 + rr;   // t_local 0..63
            *(unsigned short*)(VT + swz(col, tl * 2)) = f2bf(acc[8 + n][rr] + bias);
        }
    }
    __syncthreads();
    #pragma unroll
    for (int it = 0; it < 2; ++it) {
        int c = it * 256 + tid;
        int h = c >> 3, c4 = c & 7;          // 8 int4 per 128B row
        *(int4*)(Vt + ((long)b * KD + h) * TCTX + tb + c4 * 8) =
            *(const int4*)(VT + swz(h, c4 * 16));
    }
}

// ---------------------------------------------------------------------------
// Flash attention v3: 2-wave blocks, 32 q-rows, defer-max online softmax.
// Grid 1024 (8 b x 128 q-tiles), 36KB LDS -> 4 blocks/CU (8 waves/CU).
// Swapped QK^T (A=K, B=Q): lane owns q-row t=lr, 16 s-values in-register.
// Fast path (common): per-lane 15-fmax + __all vote; NO cross-lane ops,
//   NO O-rescale (m unchanged, P bounded by 2^8). Slow path (~1 tile/q-tile):
//   2-shfl row max-reduce + O rescale via 4 broadcasts.
// sum kept as per-lane PARTIAL (m row-uniform => scl identical across the
//   row's 4 lanes); reduced once in the epilogue.
// Degenerate rows (fully masked, incl. t=4095): m stays MASK2 => P=exp2(0)=1
//   uniform (exact reference -1e10 semantics); zeroed later by scl=0 if a
//   real entry appears. No special cases needed.
// ---------------------------------------------------------------------------
__global__ __launch_bounds__(128) void attn_kernel(
    const unsigned short* __restrict__ Qb,
    const unsigned short* __restrict__ Kb,
    const unsigned short* __restrict__ Vt,
    float* __restrict__ out)
{
    __shared__ __align__(16) char lds[36 * 1024];
    // buf B: K at B*16KB, V at B*16KB+8KB ; Q/P per-wave at 32KB + w*2KB

    const int bid = blockIdx.x;
    const int b   = bid & 7;
    const int qr  = bid >> 3;              // 0..127
    const int qi  = (qr + 127) & 127;      // heavy tiles launch first
    const int t0  = qi * 32;
    const int tid = threadIdx.x, lane = tid & 63, w = tid >> 6;   // w in {0,1}
    const int lr  = lane & 15, lg = lane >> 4;
    const int tg  = t0 + w * 16 + lr;      // this lane's q-row (softmax owner)

    char* QP = lds + 32 * 1024 + w * 2048; // per-wave Q (then P) region

    const unsigned short* Qg  = Qb + ((long)b * TCTX + t0 + w * 16) * KD;
    const unsigned short* Kg0 = Kb + (long)b * TCTX * KD;
    const unsigned short* Vg0 = Vt + (long)b * KD * TCTX;

    // 128B-row staging mapping: row = chunk*8 + (lane>>3), block = lane&7
    const int srow = lane >> 3;
    const int sblk = lane & 7;

    // stage this wave's 16 Q rows (2KB), pre-swizzled source
    #pragma unroll
    for (int j = 0; j < 2; ++j) {
        int r = j * 8 + srow;
        int c = sblk ^ (r & 7);
        gl_lds16(Qg + r * KD + c * 8, QP + j * 1024);
    }

    auto stageKV = [&](int buf, int si) {
        char* Kl = lds + buf * 16 * 1024;
        char* Vl = Kl + 8 * 1024;
        const unsigned short* Kg = Kg0 + si * 64 * KD;
        const unsigned short* Vg = Vg0 + si * 64;
        #pragma unroll
        for (int j = 0; j < 4; ++j) {
            int chunk = w * 4 + j;             // 2 waves split the 8 chunks
            int r = chunk * 8 + srow;
            int c = sblk ^ (r & 7);
            gl_lds16(Kg + r * KD + c * 8, Kl + chunk * 1024);
            gl_lds16(Vg + (long)r * TCTX + c * 8, Vl + chunk * 1024);
        }
    };

    const int s_begin = (qi == 127) ? 0 : (qi >> 1);
    stageKV(0, s_begin);
    __syncthreads();                       // Q + buf0 ready

    // hoist Q fragments (B-operand: lane c=lr holds Q[t=lr][k])
    bf16x8 qf[2];
    #pragma unroll
    for (int kh = 0; kh < 2; ++kh)
        qf[kh] = *(const bf16x8*)(QP + swz(lr, kh * 64 + lg * 16));

    float m2 = MASK2, sum_p = 0.f;         // per-lane partial sum
    f32x4 O[4];
    #pragma unroll
    for (int n = 0; n < 4; ++n) O[n] = fzero4();

    int cur = 0;
    for (int si = s_begin; si < 64; ++si) {
        if (si < 63) stageKV(cur ^ 1, si + 1);
        char* Kl = lds + cur * 16 * 1024;
        char* Vl = Kl + 8 * 1024;

        // ---- QK^T (swapped): C[s][t], t = lr per lane, 16 s/lane ----
        f32x4 sc[4];
        #pragma unroll
        for (int mi = 0; mi < 4; ++mi) sc[mi] = fzero4();
        #pragma unroll
        for (int kh = 0; kh < 2; ++kh) {
            #pragma unroll
            for (int mi = 0; mi < 4; ++mi) {
                bf16x8 kf = *(const bf16x8*)(Kl + swz(mi * 16 + lr, kh * 64 + lg * 16));
                sc[mi] = __builtin_amdgcn_mfma_f32_16x16x32_bf16(kf, qf[kh], sc[mi], 0, 0, 0);
            }
        }

        // ---- masked scores in exp2 domain ----
        const int thr = tg - si * 64;      // mask if s_local <= thr
        float s2v[4][4];
        #pragma unroll
        for (int mi = 0; mi < 4; ++mi)
            #pragma unroll
            for (int rr = 0; rr < 4; ++rr) {
                int sl = mi * 16 + lg * 4 + rr;
                float v = sc[mi][rr] * SCALE2;
                s2v[mi][rr] = (sl <= thr) ? MASK2 : v;
            }

        // ---- defer-max online softmax ----
        float pml = s2v[0][0];
        #pragma unroll
        for (int mi = 0; mi < 4; ++mi)
            #pragma unroll
            for (int rr = 0; rr < 4; ++rr) pml = fmaxf(pml, s2v[mi][rr]);

        if (!__all(pml - m2 <= 8.0f)) {    // rare: max grew; full rescale
            float pm = pml;
            pm = fmaxf(pm, __shfl_xor(pm, 16, 64));
            pm = fmaxf(pm, __shfl_xor(pm, 32, 64));   // row-uniform max
            float mnew = fmaxf(m2, pm);
            float scl = __builtin_amdgcn_exp2f(m2 - mnew);
            m2 = mnew;
            sum_p *= scl;
            #pragma unroll
            for (int rr = 0; rr < 4; ++rr) {
                float sb = __shfl(scl, lg * 4 + rr, 64);
                #pragma unroll
                for (int n = 0; n < 4; ++n) O[n][rr] *= sb;
            }
        }
        float ls = 0.f;
        #pragma unroll
        for (int mi = 0; mi < 4; ++mi)
            #pragma unroll
            for (int rr = 0; rr < 4; ++rr) {
                s2v[mi][rr] = __builtin_amdgcn_exp2f(s2v[mi][rr] - m2);
                ls += s2v[mi][rr];
            }
        sum_p += ls;                        // per-lane partial; no shfl

        // ---- pack P (bf16 pairs) -> per-wave LDS region ----
        #pragma unroll
        for (int mi = 0; mi < 4; ++mi) {
            unsigned lo = cvtpk_bf16(s2v[mi][0], s2v[mi][1]);
            unsigned hi = cvtpk_bf16(s2v[mi][2], s2v[mi][3]);
            *(uint2*)(QP + swz(lr, mi * 32 + lg * 8)) = make_uint2(lo, hi);
        }

        // ---- PV: O += P @ V ----
        #pragma unroll
        for (int kh = 0; kh < 2; ++kh) {
            bf16x8 ap = *(const bf16x8*)(QP + swz(lr, kh * 64 + lg * 16));
            #pragma unroll
            for (int n = 0; n < 4; ++n) {
                bf16x8 bv = *(const bf16x8*)(Vl + swz(n * 16 + lr, kh * 64 + lg * 16));
                O[n] = __builtin_amdgcn_mfma_f32_16x16x32_bf16(ap, bv, O[n], 0, 0, 0);
            }
        }
        __syncthreads();                    // next-tile DMA landed; frees cur
        cur ^= 1;
    }

    // ---- epilogue: reduce partial sums, out = O / sum ----
    float sr = sum_p;
    sr += __shfl_xor(sr, 16, 64);
    sr += __shfl_xor(sr, 32, 64);           // full row sum
    #pragma unroll
    for (int rr = 0; rr < 4; ++rr) {
        float sb = __shfl(sr, lg * 4 + rr, 64);
        int t = t0 + w * 16 + lg * 4 + rr;
        #pragma unroll
        for (int n = 0; n < 4; ++n)
            out[((long)b * TCTX + t) * KD + n * 16 + lr] = O[n][rr] / sb;
    }
}

extern "C" void kernel_launch(void* const* d_in, const int* in_sizes, int n_in,
                              void* d_out, int out_size, void* d_ws, size_t ws_size,
                              hipStream_t stream) {
    const float* emb = (const float*)d_in[0];
    const float* kw1 = (const float*)d_in[1];
    const float* kb1 = (const float*)d_in[2];
    const float* kw2 = (const float*)d_in[3];
    const float* kb2 = (const float*)d_in[4];
    const float* qw1 = (const float*)d_in[5];
    const float* qb1 = (const float*)d_in[6];
    const float* qw2 = (const float*)d_in[7];
    const float* qb2 = (const float*)d_in[8];
    const float* vw  = (const float*)d_in[9];
    const float* vb  = (const float*)d_in[10];

    unsigned short* Qb  = (unsigned short*)d_ws;               // 4 MB
    unsigned short* Kb  = Qb + (size_t)NB * TCTX * KD;         // 4 MB
    unsigned short* Vt  = Kb + (size_t)NB * TCTX * KD;         // 4 MB, [b][h][t]
    unsigned short* W1p = Vt + (size_t)NB * TCTX * KD;         // 384 KB
    unsigned short* W2p = W1p + 196608;                        // 16 KB

    hipLaunchKernelGGL(prep_kernel, dim3(100), dim3(256), 0, stream,
                       kw1, qw1, vw, kw2, qw2, W1p, W2p);
    hipLaunchKernelGGL(proj_kernel, dim3(512), dim3(256), 0, stream,
                       emb, W1p, W2p, kb1, kb2, qb1, qb2, vb,
                       Qb, Kb, Vt);
    hipLaunchKernelGGL(attn_kernel, dim3(1024), dim3(128), 0, stream,
                       Qb, Kb, Vt, (float*)d_out);
}